// Round 6
// baseline (1033.090 us; speedup 1.0000x reference)
//
#include <hip/hip_runtime.h>

#define NORD 24
#define LL 32
#define MMLEN 3073

// 1/j! for j=0..25
static constexpr float INVF[26] = {
    1.0f, 1.0f, 5.0e-1f, 1.66666672e-1f, 4.16666679e-2f, 8.33333377e-3f,
    1.38888892e-3f, 1.98412701e-4f, 2.48015876e-5f, 2.75573195e-6f,
    2.75573188e-7f, 2.50521089e-8f, 2.08767563e-9f, 1.60590438e-10f,
    1.14707458e-11f, 7.64716373e-13f, 4.77947733e-14f, 2.81145725e-15f,
    1.56192069e-16f, 8.22063525e-18f, 4.11031762e-19f, 1.95729410e-20f,
    8.89679139e-22f, 3.86817017e-23f, 1.61173757e-24f, 6.44695028e-26f};

// trapezoidal pulse, f32 arithmetic replicating the jnp reference
__device__ __forceinline__ float pulsef(float ts) {
    const float rise = 5.0e-10f;
    const float w    = 9.999999999999999e-10f;
    const float e1   = 1.4999999999999998e-9f;
    const float e2   = 1.9999999999999997e-9f;
    const float fall = 5.0e-10f;
    if (ts < rise) return ts / rise;
    if (ts < e1)   return 1.0f;
    if (ts < e2)   return 1.0f - ((ts - w) - rise) / fall;
    return 0.0f;
}

// VALU-pipe cross-lane move within a 16-lane DPP row
template <int CTRL>
__device__ __forceinline__ float dpp_movf(float x) {
    return __int_as_float(__builtin_amdgcn_update_dpp(
        0, __float_as_int(x), CTRL, 0xF, 0xF, true));
}

// One term of the power recursion: t <- (M*dt) * t, midv <- new mid component.
// Layout (round-4): lane l -> branch b=l&15, quarter q=l>>4; t[i] = chain pos 16q+i.
// Branch heads (pos 0) live in DPP row 0 (lanes 0..15); midv valid in row 0 only.
__device__ __forceinline__ void term_step(float (&t)[16], float& midv,
                                          const float (&al)[16],
                                          const float (&be)[16],
                                          float cMb, bool head) {
    // mid_new = sum_b cM[b]*t_old[head_b] : DPP row all-reduce (VALU pipe)
    float hv = cMb * t[0];
    hv += dpp_movf<0xB1>(hv);    // quad_perm xor1
    hv += dpp_movf<0x4E>(hv);    // quad_perm xor2
    hv += dpp_movf<0x124>(hv);   // row_ror:4
    hv += dpp_movf<0x128>(hv);   // row_ror:8
    // chain-boundary halo (2 independent LDS-pipe ops; latency hidden by the
    // other fused stream's VALU work)
    float lv = __shfl_up(t[15], 16);   // pos 16q-1 from lane l-16 (q>0)
    float rv = __shfl_down(t[0], 16);  // pos 16q+16 from lane l+16 (q==3: be[15]==0)
    float left0 = head ? midv : lv;    // head rows couple to v_mid

    float nt[16];
    nt[0] = al[0] * left0 + be[0] * t[1];
#pragma unroll
    for (int i = 1; i < 15; ++i)
        nt[i] = al[i] * t[i - 1] + be[i] * t[i + 1];
    nt[15] = al[15] * t[14] + be[15] * rv;

    midv = hv;
#pragma unroll
    for (int i = 0; i < 16; ++i) t[i] = nt[i];
}

// One fused "unit": advances BOTH chains by one full series application.
//  F stream: zF <- E * zF          (SERIES=false)
//            zF <- dt * Phi * zF   (SERIES=true; Phi = sum A^j dt^j/(j+1)!)
//  B stream: wB <- E^T * wB
// The two term_step calls per j are independent -> 2x ILP, bpermute RT hidden.
template <bool SERIES>
__device__ __forceinline__ void unit_pair(
    float (&zF)[16], float& zFm,
    float (&wB)[16], float& wBm,
    const float (&alF)[16], const float (&beF)[16], float cMF,
    const float (&alB)[16], const float (&beB)[16], float cMB,
    bool head, float dtv)
{
    float tF[16], aF[16], tB[16], aB[16];
#pragma unroll
    for (int i = 0; i < 16; ++i) {
        tF[i] = zF[i]; aF[i] = zF[i];
        tB[i] = wB[i]; aB[i] = wB[i];
    }
    float mF = zFm, amF = zFm;
    float mB = wBm, amB = wBm;
#pragma unroll
    for (int j = 1; j <= NORD; ++j) {
        term_step(tF, mF, alF, beF, cMF, head);
        term_step(tB, mB, alB, beB, cMB, head);
        const float fF = SERIES ? INVF[j + 1] : INVF[j];
        const float fB = INVF[j];
#pragma unroll
        for (int i = 0; i < 16; ++i) {
            aF[i] = fmaf(fF, tF[i], aF[i]);
            aB[i] = fmaf(fB, tB[i], aB[i]);
        }
        amF = fmaf(fF, mF, amF);
        amB = fmaf(fB, mB, amB);
    }
    if (SERIES) {
#pragma unroll
        for (int i = 0; i < 16; ++i) zF[i] = aF[i] * dtv;
        zFm = amF * dtv;
    } else {
#pragma unroll
        for (int i = 0; i < 16; ++i) zF[i] = aF[i];
        zFm = amF;
    }
#pragma unroll
    for (int i = 0; i < 16; ++i) wB[i] = aB[i];
    wBm = amB;
}

// Meet-in-the-middle, both chains fused in ONE wave per star:
//   xm(T) = P0 . phib + P31 . z31
//   P0  = sum_{a=0}^{30} u_{63-a} w_a,  P31 = sum_{a=0}^{32} u_{32-a} w_a
//   w_a = (E^T)^a e_mid,  z31 = E^31 phib
__global__ __launch_bounds__(64, 1) void sspuf_fused(
    const int*   __restrict__ swp,
    const float* __restrict__ mismatch,
    const float* __restrict__ gm_c,
    const float* __restrict__ gm_l,
    const float* __restrict__ c_val,
    const float* __restrict__ l_val,
    const float* __restrict__ tp,
    float*       __restrict__ out)
{
    const int star = blockIdx.x;
    const int l = threadIdx.x;          // 0..63
    const int b = l & 15;               // branch
    const int q = l >> 4;               // quarter of the 64-state chain
    const bool head = (q == 0);
    const float dt = tp[0] / 64.0f;

    const float* mm = mismatch + star * MMLEN;
    const float* mb = mm + b * 192;
    const float swb   = (float)swp[b];
    const float c_mid = 1e-9f * (mm[MMLEN - 1] * c_val[LL]);

    const int P0i = q << 4;

    // ---------------- forward coefficients of (A*dt) ----------------
    // pos 2k = i[b,k], pos 2k+1 = v[b,k]
    float alF[16], beF[16];
#pragma unroll
    for (int i = 0; i < 16; ++i) {
        int p = P0i + i, k = p >> 1;
        if ((p & 1) == 0) {
            float Lm = 1e-9f * (mb[160 + k] * l_val[k]);
            float a  = dt * ((mb[64 + 2 * k] * gm_l[2 * k]) / Lm);
            if (k == 0) a *= swb;       // left neighbor is v_mid
            alF[i] = a;
            beF[i] = -dt * ((mb[64 + 2 * k + 1] * gm_l[2 * k + 1]) / Lm);
        } else {
            float C = 1e-9f * (mb[128 + k] * c_val[k]);
            alF[i] = dt * ((mb[2 * k] * gm_c[2 * k]) / C);
            beF[i] = (k < 31) ? (-dt * ((mb[2 * k + 1] * gm_c[2 * k + 1]) / C))
                              : 0.0f;
        }
    }
    const float cMF = -dt * (swb / c_mid);

    // ---------------- backward coefficients of (A^T*dt) ----------------
    // alT[p] = dt*A[p-1][p] (p=0: mid coupling), beT[p] = dt*A[p+1][p]
    float alB[16], beB[16];
#pragma unroll
    for (int i = 0; i < 16; ++i) {
        int p = P0i + i, k = p >> 1;
        if ((p & 1) == 0) {
            if (p == 0) {
                alB[i] = -dt * (swb / c_mid);
            } else {
                float Cm1 = 1e-9f * (mb[128 + (k - 1)] * c_val[k - 1]);
                alB[i] = -dt * ((mb[2 * (k - 1) + 1] * gm_c[2 * (k - 1) + 1]) / Cm1);
            }
            float C = 1e-9f * (mb[128 + k] * c_val[k]);
            beB[i] = dt * ((mb[2 * k] * gm_c[2 * k]) / C);
        } else {
            float Lm = 1e-9f * (mb[160 + k] * l_val[k]);
            alB[i] = -dt * ((mb[64 + 2 * k + 1] * gm_l[2 * k + 1]) / Lm);
            if (k < 31) {
                float Lp = 1e-9f * (mb[160 + (k + 1)] * l_val[k + 1]);
                beB[i] = dt * ((mb[64 + 2 * (k + 1)] * gm_l[2 * (k + 1)]) / Lp);
            } else {
                beB[i] = 0.0f;
            }
        }
    }
    float Lm0 = 1e-9f * (mb[160] * l_val[0]);
    const float cMB = dt * ((swb * (mb[64] * gm_l[0])) / Lm0);

    // ---------------- state init ----------------
    float zF[16], wB[16], Pa[16], Pb[16], phib[16];
#pragma unroll
    for (int i = 0; i < 16; ++i) {
        zF[i] = 0.0f; wB[i] = 0.0f; Pa[i] = 0.0f; Pb[i] = 0.0f;
    }
    float zFm = 1.0f / c_mid;   // Bv (mid component); valid in row 0, used there only
    float wBm = 1.0f;           // e_mid
    float Pam = 0.0f, Pbm = 0.0f;

    // fold(a=0) with w_0 = e_mid
    {
        const float ua = pulsef((63.0f + 0.5f) * dt);
        const float ub = pulsef((32.0f + 0.5f) * dt);
#pragma unroll
        for (int i = 0; i < 16; ++i) {
            Pa[i] = fmaf(ua, wB[i], Pa[i]);
            Pb[i] = fmaf(ub, wB[i], Pb[i]);
        }
        Pam = fmaf(ua, wBm, Pam);
        Pbm = fmaf(ub, wBm, Pbm);
    }

    // unit 0: F = phib series (Phi*Bv*dt), B = w_0 -> w_1
    unit_pair<true>(zF, zFm, wB, wBm, alF, beF, cMF, alB, beB, cMB, head, dt);
    // save phib (zF will be overwritten by the 31 E-applies)
    float phibm = zFm;
#pragma unroll
    for (int i = 0; i < 16; ++i) phib[i] = zF[i];
    // fold(1)
    {
        const float ua = pulsef((62.0f + 0.5f) * dt);
        const float ub = pulsef((31.0f + 0.5f) * dt);
#pragma unroll
        for (int i = 0; i < 16; ++i) {
            Pa[i] = fmaf(ua, wB[i], Pa[i]);
            Pb[i] = fmaf(ub, wB[i], Pb[i]);
        }
        Pam = fmaf(ua, wBm, Pam);
        Pbm = fmaf(ub, wBm, Pbm);
    }

    // units 1..31: F: z -> E z (31 applies -> z31); B: w_a -> w_{a+1}, fold(a+1)
    for (int a = 1; a <= 31; ++a) {
        unit_pair<false>(zF, zFm, wB, wBm, alF, beF, cMF, alB, beB, cMB, head, dt);
        const int an = a + 1;
        const float ua = (an <= 30) ? pulsef(((float)(63 - an) + 0.5f) * dt) : 0.0f;
        const float ub = pulsef(((float)(32 - an) + 0.5f) * dt);
#pragma unroll
        for (int i = 0; i < 16; ++i) {
            Pa[i] = fmaf(ua, wB[i], Pa[i]);
            Pb[i] = fmaf(ub, wB[i], Pb[i]);
        }
        Pam = fmaf(ua, wBm, Pam);
        Pbm = fmaf(ub, wBm, Pbm);
    }

    // ---------------- epilogue: all in-register ----------------
    float part = 0.0f;
#pragma unroll
    for (int i = 0; i < 16; ++i)
        part += Pa[i] * phib[i] + Pb[i] * zF[i];
    if (l == 0)
        part += Pam * phibm + Pbm * zFm;
    // 64-lane sum: DPP row reduce + cross-row shuffles
    part += dpp_movf<0xB1>(part);
    part += dpp_movf<0x4E>(part);
    part += dpp_movf<0x124>(part);
    part += dpp_movf<0x128>(part);
    part += __shfl_xor(part, 16);
    part += __shfl_xor(part, 32);
    if (l == 0) atomicAdd(out, (star == 0) ? part : -part);
}

extern "C" void kernel_launch(void* const* d_in, const int* in_sizes, int n_in,
                              void* d_out, int out_size, void* d_ws, size_t ws_size,
                              hipStream_t stream) {
    const int*   swp      = (const int*)d_in[0];
    const float* mismatch = (const float*)d_in[1];
    const float* gm_c     = (const float*)d_in[2];
    const float* gm_l     = (const float*)d_in[3];
    const float* c_val    = (const float*)d_in[4];
    const float* l_val    = (const float*)d_in[5];
    const float* tp       = (const float*)d_in[6];
    float* out = (float*)d_out;

    hipMemsetAsync(out, 0, sizeof(float), stream);
    sspuf_fused<<<dim3(2), dim3(64), 0, stream>>>(
        swp, mismatch, gm_c, gm_l, c_val, l_val, tp, out);
}